// Round 1
// 823.051 us; speedup vs baseline: 1.2481x; 1.2481x over previous
//
#include <hip/hip_runtime.h>

// SNN B=128, D0=512, T=512, dims 1024/1024/512, DECAY=0.5, THRESH=0.3
// Round 12: bit-packed spike trains between layers.
//  - L0 GEMM unchanged (Xh/Xl + Wh/Wl 3-term, BK=32, 2-barrier); epilogue now
//    ballot-transposes the spike masks and stores 2 u64/thread/slice.
//  - L1/L2: A comes from the bit train (16 KB LDS tile per slice, loaded once),
//    expanded bits->bf16{0,1} in VGPRs (exact). B hi/lo staged at BK=64
//    (half the barriers). 48 KB LDS -> 3 blocks/CU (__launch_bounds__(256,3)).
//  - Spike trains: 134 MB bf16 -> 8.4 MB bits each; epilogue stores 128->2 per
//    thread. Accumulation order per acc element identical to r11 (absmax=0).
// Bit layout per (s,b): 128 rows (t) x 128 B; u64 block j8 (k=j8*64..+63)
// stored at slot (j8 ^ (t&15)) -> conflict-free ds_read_b64 in consumer.

typedef __bf16 bf16;
typedef __attribute__((ext_vector_type(8))) __bf16 bf16x8;
typedef __attribute__((ext_vector_type(16))) float f32x16;
typedef unsigned long long u64;

#define B_   128
#define D0_  512
#define T_   512
#define TS_  128
#define N1_  1024
#define N2_  1024
#define N3_  512
#define MFMA32(a,b,c) __builtin_amdgcn_mfma_f32_32x32x16_bf16((a),(b),(c),0,0,0)

#define GL2LDS(g, l) __builtin_amdgcn_global_load_lds( \
    (const __attribute__((address_space(1))) void*)(g), \
    (__attribute__((address_space(3))) void*)(l), 16, 0, 0)

// ---------- setup ----------

__global__ __launch_bounds__(256)
void split_w(const float* __restrict__ W, bf16* __restrict__ WTh, bf16* __restrict__ WTl,
             int K, int N)
{
    __shared__ float tile[32][33];
    const int k0 = blockIdx.x * 32, n0 = blockIdx.y * 32;
    const int tx = threadIdx.x & 31, ty = threadIdx.x >> 5;
#pragma unroll
    for (int r = 0; r < 4; ++r)
        tile[ty + r * 8][tx] = W[(size_t)(k0 + ty + r * 8) * N + n0 + tx];
    __syncthreads();
#pragma unroll
    for (int r = 0; r < 4; ++r) {
        int nl = ty + r * 8;
        float v = tile[tx][nl];
        bf16 h = (bf16)v;
        size_t o = (size_t)(n0 + nl) * K + k0 + tx;
        WTh[o] = h;
        WTl[o] = (bf16)(v - (float)h);
    }
}

// x [B][D0][T] fp32 -> Xh/Xl slice-major [s][b][tl][D0] bf16 (hi/lo)
__global__ __launch_bounds__(256)
void split_x(const float* __restrict__ in, bf16* __restrict__ Xh, bf16* __restrict__ Xl)
{
    __shared__ float tile[32][33];
    const int b = blockIdx.z, d0 = blockIdx.x * 32, t0 = blockIdx.y * 32;
    const int tx = threadIdx.x & 31, ty = threadIdx.x >> 5;
#pragma unroll
    for (int r = 0; r < 4; ++r)
        tile[ty + r * 8][tx] = in[((size_t)b * D0_ + d0 + ty + r * 8) * T_ + t0 + tx];
    __syncthreads();
    const int s = t0 >> 7;
#pragma unroll
    for (int r = 0; r < 4; ++r) {
        int t  = t0 + ty + r * 8;
        int tl = t & (TS_ - 1);
        float v = tile[tx][ty + r * 8];
        bf16 h = (bf16)v;
        size_t o = (((size_t)s * B_ + b) * TS_ + tl) * D0_ + d0 + tx;
        Xh[o] = h;
        Xl[o] = (bf16)(v - (float)h);
    }
}

// 8 bits -> bf16x8 of {0.0, 1.0} (exact)
__device__ __forceinline__ bf16x8 expand8(unsigned v)
{
    union { unsigned u[4]; bf16x8 h; } r;
#pragma unroll
    for (int i = 0; i < 4; ++i) {
        r.u[i] = (((v >> (2 * i)) & 1u) ? 0x3F80u : 0u) |
                 (((v >> (2 * i + 1)) & 1u) ? 0x3F800000u : 0u);
    }
    return r.h;
}

// ---------- layer 0: Xh/Xl @ W0 (3-term), BK=32, unchanged GEMM core ----------
__global__ __launch_bounds__(256)
void snn_layer0(const bf16* __restrict__ Ah, const bf16* __restrict__ Al,
                const bf16* __restrict__ WTh, const bf16* __restrict__ WTl,
                u64* __restrict__ bitsOut)
{
    constexpr int K = D0_;
    __shared__ char smem[32768];
    bf16* sAh = (bf16*)smem;
    bf16* sAl = (bf16*)(smem + 8192);
    bf16* sBh = (bf16*)(smem + 16384);
    bf16* sBl = (bf16*)(smem + 24576);
    float* If = (float*)smem;                              // overlay [2][64][64] f32

    const int tid = threadIdx.x, lane = tid & 63, w = tid >> 6;
    const int wm = w & 1, wn = w >> 1;
    const int l31 = lane & 31, kh = lane >> 5;
    const int b = blockIdx.x;
    const int nb = blockIdx.y * 128;

    const int i4 = lane >> 2, c4 = lane & 3;
    const int csrc = c4 ^ ((i4 >> 1) & 3);
    const bf16* gBh = WTh + (size_t)(nb + w * 32 + i4) * K + csrc * 8;
    const bf16* gBl = WTl + (size_t)(nb + w * 32 + i4) * K + csrc * 8;
    bf16* lA  = sAh + w * 32 * 32;
    bf16* lAl = sAl + w * 32 * 32;
    bf16* lBh = sBh + w * 32 * 32;
    bf16* lBl = sBl + w * 32 * 32;

    int rA[2], rB[2], swA[2], swB[2];
#pragma unroll
    for (int i = 0; i < 2; ++i) {
        rA[i] = wm * 64 + i * 32 + l31;
        rB[i] = wn * 64 + i * 32 + l31;
        swA[i] = (rA[i] >> 1) & 3;
        swB[i] = (rB[i] >> 1) & 3;
    }

    float cm = 0.f, cs = 0.f;
    const int scol = tid & 63;
    float* Ifb = If + (tid >> 6) * 4096;

#pragma unroll 1
    for (int s = 0; s < T_ / TS_; ++s) {
        const size_t arow = ((size_t)s * B_ + b) * TS_;
        const bf16* gA  = Ah + (arow + w * 32 + i4) * K + csrc * 8;
        const bf16* gAl = Al + (arow + w * 32 + i4) * K + csrc * 8;

        f32x16 acc[2][2] = {};

#pragma unroll 1
        for (int ks = 0; ks < K / 32; ++ks) {
            const int go = ks * 32;
            __syncthreads();
#pragma unroll
            for (int inst = 0; inst < 2; ++inst) {
                GL2LDS(gA  + (size_t)inst * 16 * K + go, lA  + inst * 16 * 32);
                GL2LDS(gAl + (size_t)inst * 16 * K + go, lAl + inst * 16 * 32);
                GL2LDS(gBh + (size_t)inst * 16 * K + go, lBh + inst * 16 * 32);
                GL2LDS(gBl + (size_t)inst * 16 * K + go, lBl + inst * 16 * 32);
            }
            __syncthreads();

            bf16x8 a[2][2], al2[2][2];
#pragma unroll
            for (int mi = 0; mi < 2; ++mi)
#pragma unroll
                for (int h = 0; h < 2; ++h) {
                    const int off = rA[mi] * 32 + (((2 * h + kh) ^ swA[mi]) * 8);
                    a[mi][h]   = *(const bf16x8*)(sAh + off);
                    al2[mi][h] = *(const bf16x8*)(sAl + off);
                }
#pragma unroll
            for (int ni = 0; ni < 2; ++ni) {
#pragma unroll
                for (int h = 0; h < 2; ++h) {
                    const int off = rB[ni] * 32 + (((2 * h + kh) ^ swB[ni]) * 8);
                    bf16x8 bh = *(const bf16x8*)(sBh + off);
                    bf16x8 bl = *(const bf16x8*)(sBl + off);
#pragma unroll
                    for (int mi = 0; mi < 2; ++mi) {
                        acc[mi][ni] = MFMA32(a[mi][h], bh, acc[mi][ni]);
                        acc[mi][ni] = MFMA32(al2[mi][h], bh, acc[mi][ni]);
                        acc[mi][ni] = MFMA32(a[mi][h], bl, acc[mi][ni]);
                    }
                }
            }
        }

        // ---- epilogue: 2-phase LIF scan, ballot bit-transpose store ----
        u64 word0 = 0, word1 = 0;
        __syncthreads();
        if (wm == 0) {
#pragma unroll
            for (int ni = 0; ni < 2; ++ni)
#pragma unroll
                for (int mi = 0; mi < 2; ++mi)
#pragma unroll
                    for (int r = 0; r < 16; ++r) {
                        const int tt = mi * 32 + (r & 3) + 8 * (r >> 2) + 4 * kh;
                        If[wn * 4096 + tt * 64 + ni * 32 + l31] = acc[mi][ni][r];
                    }
        }
        __syncthreads();
        if (tid < 128) {
            float m = cm, sp = cs;
#pragma unroll 4
            for (int tt = 0; tt < 64; ++tt) {
                m = m * 0.5f * (1.0f - sp) + Ifb[tt * 64 + scol];
                const bool fire = m > 0.3f;
                sp = fire ? 1.0f : 0.0f;
                u64 bal = __ballot(fire);
                if ((tid & 63) == tt) word0 = bal;
            }
            cm = m; cs = sp;
        }
        __syncthreads();
        if (wm == 1) {
#pragma unroll
            for (int ni = 0; ni < 2; ++ni)
#pragma unroll
                for (int mi = 0; mi < 2; ++mi)
#pragma unroll
                    for (int r = 0; r < 16; ++r) {
                        const int tt = mi * 32 + (r & 3) + 8 * (r >> 2) + 4 * kh;
                        If[wn * 4096 + tt * 64 + ni * 32 + l31] = acc[mi][ni][r];
                    }
        }
        __syncthreads();
        if (tid < 128) {
            float m = cm, sp = cs;
#pragma unroll 4
            for (int tt = 0; tt < 64; ++tt) {
                m = m * 0.5f * (1.0f - sp) + Ifb[tt * 64 + scol];
                const bool fire = m > 0.3f;
                sp = fire ? 1.0f : 0.0f;
                u64 bal = __ballot(fire);
                if ((tid & 63) == tt) word1 = bal;
            }
            cm = m; cs = sp;
            u64* dst = bitsOut + ((size_t)s * B_ + b) * 2048;  // 128 rows x 16 u64
            const int j8 = (nb >> 6) + (tid >> 6);
            const int t0 = tid & 63, t1 = 64 + (tid & 63);
            dst[t0 * 16 + (j8 ^ (t0 & 15))] = word0;
            dst[t1 * 16 + (j8 ^ (t1 & 15))] = word1;
        }
    }
}

// ---------- layers 1/2: bit-packed A, BK=64 ----------
template<bool WRITE_BITS>
__global__ __launch_bounds__(256, 3)
void snn_layer_bits(const u64* __restrict__ bitsIn,
                    const bf16* __restrict__ WTh, const bf16* __restrict__ WTl,
                    u64* __restrict__ bitsOut, float* __restrict__ outp, int N)
{
    constexpr int K = 1024;
    __shared__ char smem[49152];
    char* bitsLds = smem;                       // [0,16K): bit tile [128 t][128 B]
    bf16* sBh = (bf16*)(smem + 16384);          // [16K,32K): B hi [128][64]
    bf16* sBl = (bf16*)(smem + 32768);          // [32K,48K): B lo [128][64]
    float* If  = (float*)(smem + 16384);        // epilogue overlay (32 KB)

    const int tid = threadIdx.x, lane = tid & 63, w = tid >> 6;
    const int wm = w & 1, wn = w >> 1;
    const int l31 = lane & 31, kh = lane >> 5;
    const int b = blockIdx.x;
    const int nb = blockIdx.y * 128;

    // B staging geometry (BK=64): lane = (row i8, chunk c8); chunk pre-swizzled
    const int i8 = lane >> 3, c8 = lane & 7;
    const bf16* gBh = WTh + (size_t)(nb + w * 32 + i8) * K + (c8 ^ i8) * 8;
    const bf16* gBl = WTl + (size_t)(nb + w * 32 + i8) * K + (c8 ^ i8) * 8;
    bf16* lBh = sBh + (w * 32) * 64;
    bf16* lBl = sBl + (w * 32) * 64;

    int rA[2], rB[2];
#pragma unroll
    for (int i = 0; i < 2; ++i) {
        rA[i] = wm * 64 + i * 32 + l31;
        rB[i] = wn * 64 + i * 32 + l31;
    }
    const int sw7 = l31 & 7, sw15 = l31 & 15;

    float cm = 0.f, cs = 0.f;
    const int scol = tid & 63;
    float* Ifb = If + (tid >> 6) * 4096;

#pragma unroll 1
    for (int s = 0; s < T_ / TS_; ++s) {
        // stage bit tile (16 KB, linear; swizzle baked into global layout).
        // Issued before the first barrier so it overlaps the previous slice's
        // scan (disjoint LDS region, prior reads already drained).
        {
            const char* src = (const char*)bitsIn + ((size_t)s * B_ + b) * 16384;
#pragma unroll
            for (int i = 0; i < 4; ++i)
                GL2LDS(src + (w * 4 + i) * 1024 + lane * 16,
                       bitsLds + (w * 4 + i) * 1024);
        }

        f32x16 acc[2][2] = {};

#pragma unroll 1
        for (int ks = 0; ks < K / 64; ++ks) {
            const int go = ks * 64;
            __syncthreads();
#pragma unroll
            for (int inst = 0; inst < 4; ++inst) {
                GL2LDS(gBh + (size_t)(inst * 8) * K + go, lBh + inst * 8 * 64);
                GL2LDS(gBl + (size_t)(inst * 8) * K + go, lBl + inst * 8 * 64);
            }
            __syncthreads();

            u64 wA0 = *(const u64*)(bitsLds + rA[0] * 128 + ((ks ^ sw15) << 3)) >> (8 * kh);
            u64 wA1 = *(const u64*)(bitsLds + rA[1] * 128 + ((ks ^ sw15) << 3)) >> (8 * kh);

#pragma unroll
            for (int h = 0; h < 4; ++h) {
                bf16x8 a0 = expand8((unsigned)(wA0 >> (16 * h)) & 0xFFu);
                bf16x8 a1 = expand8((unsigned)(wA1 >> (16 * h)) & 0xFFu);
#pragma unroll
                for (int ni = 0; ni < 2; ++ni) {
                    const int off = rB[ni] * 64 + (((2 * h + kh) ^ sw7) << 3);
                    bf16x8 bh = *(const bf16x8*)(sBh + off);
                    bf16x8 bl = *(const bf16x8*)(sBl + off);
                    acc[0][ni] = MFMA32(a0, bh, acc[0][ni]);
                    acc[0][ni] = MFMA32(a0, bl, acc[0][ni]);
                    acc[1][ni] = MFMA32(a1, bh, acc[1][ni]);
                    acc[1][ni] = MFMA32(a1, bl, acc[1][ni]);
                }
            }
        }

        // ---- epilogue: 2-phase LIF scan + ballot bit-transpose ----
        u64 word0 = 0, word1 = 0;
        __syncthreads();
        if (wm == 0) {
#pragma unroll
            for (int ni = 0; ni < 2; ++ni)
#pragma unroll
                for (int mi = 0; mi < 2; ++mi)
#pragma unroll
                    for (int r = 0; r < 16; ++r) {
                        const int tt = mi * 32 + (r & 3) + 8 * (r >> 2) + 4 * kh;
                        If[wn * 4096 + tt * 64 + ni * 32 + l31] = acc[mi][ni][r];
                    }
        }
        __syncthreads();
        if (tid < 128) {
            float m = cm, sp = cs;
#pragma unroll 4
            for (int tt = 0; tt < 64; ++tt) {
                m = m * 0.5f * (1.0f - sp) + Ifb[tt * 64 + scol];
                const bool fire = m > 0.3f;
                sp = fire ? 1.0f : 0.0f;
                if constexpr (WRITE_BITS) {
                    u64 bal = __ballot(fire);
                    if ((tid & 63) == tt) word0 = bal;
                }
            }
            cm = m; cs = sp;
        }
        __syncthreads();
        if (wm == 1) {
#pragma unroll
            for (int ni = 0; ni < 2; ++ni)
#pragma unroll
                for (int mi = 0; mi < 2; ++mi)
#pragma unroll
                    for (int r = 0; r < 16; ++r) {
                        const int tt = mi * 32 + (r & 3) + 8 * (r >> 2) + 4 * kh;
                        If[wn * 4096 + tt * 64 + ni * 32 + l31] = acc[mi][ni][r];
                    }
        }
        __syncthreads();
        if (tid < 128) {
            float m = cm, sp = cs;
#pragma unroll 4
            for (int tt = 0; tt < 64; ++tt) {
                m = m * 0.5f * (1.0f - sp) + Ifb[tt * 64 + scol];
                const bool fire = m > 0.3f;
                sp = fire ? 1.0f : 0.0f;
                if constexpr (WRITE_BITS) {
                    u64 bal = __ballot(fire);
                    if ((tid & 63) == tt) word1 = bal;
                }
            }
            cm = m; cs = sp;
            if constexpr (WRITE_BITS) {
                u64* dst = bitsOut + ((size_t)s * B_ + b) * 2048;
                const int j8 = (nb >> 6) + (tid >> 6);
                const int t0 = tid & 63, t1 = 64 + (tid & 63);
                dst[t0 * 16 + (j8 ^ (t0 & 15))] = word0;
                dst[t1 * 16 + (j8 ^ (t1 & 15))] = word1;
            } else {
                if (s == T_ / TS_ - 1)
                    outp[(size_t)b * N + nb + tid] = cs;   // spike at t=511
            }
        }
    }
}

extern "C" void kernel_launch(void* const* d_in, const int* in_sizes, int n_in,
                              void* d_out, int out_size, void* d_ws, size_t ws_size,
                              hipStream_t stream)
{
    const float* x  = (const float*)d_in[0];
    const float* w0 = (const float*)d_in[1];
    const float* w1 = (const float*)d_in[2];
    const float* w2 = (const float*)d_in[3];
    float* out = (float*)d_out;

    char* p = (char*)d_ws;
    bf16* w0h = (bf16*)p;  p += (size_t)N1_ * D0_ * 2;
    bf16* w0l = (bf16*)p;  p += (size_t)N1_ * D0_ * 2;
    bf16* w1h = (bf16*)p;  p += (size_t)N2_ * N1_ * 2;
    bf16* w1l = (bf16*)p;  p += (size_t)N2_ * N1_ * 2;
    bf16* w2h = (bf16*)p;  p += (size_t)N3_ * N2_ * 2;
    bf16* w2l = (bf16*)p;  p += (size_t)N3_ * N2_ * 2;
    bf16* Xh  = (bf16*)p;  p += (size_t)T_ * B_ * D0_ * 2;          // 67 MB
    bf16* Xl  = (bf16*)p;  p += (size_t)T_ * B_ * D0_ * 2;          // 67 MB
    u64* bits0 = (u64*)p;  p += (size_t)(T_/TS_) * B_ * TS_ * (N1_/8);  // 8.4 MB
    u64* bits1 = (u64*)p;  p += (size_t)(T_/TS_) * B_ * TS_ * (N2_/8);  // 8.4 MB

    split_w<<<dim3(D0_/32, N1_/32), 256, 0, stream>>>(w0, w0h, w0l, D0_, N1_);
    split_w<<<dim3(N1_/32, N2_/32), 256, 0, stream>>>(w1, w1h, w1l, N1_, N2_);
    split_w<<<dim3(N2_/32, N3_/32), 256, 0, stream>>>(w2, w2h, w2l, N2_, N3_);
    split_x<<<dim3(D0_/32, T_/32, B_), 256, 0, stream>>>(x, Xh, Xl);

    // L0: X@w0 (3-term split) + LIF -> bit train
    snn_layer0<<<dim3(B_, N1_/128), 256, 0, stream>>>(Xh, Xl, w0h, w0l, bits0);
    // L1: bits0@w1 + LIF -> bit train
    snn_layer_bits<true ><<<dim3(B_, N2_/128), 256, 0, stream>>>(
        bits0, w1h, w1l, bits1, nullptr, N2_);
    // L2: bits1@w2 + LIF -> final spikes to d_out
    snn_layer_bits<false><<<dim3(B_, N3_/128), 256, 0, stream>>>(
        bits1, w2h, w2l, nullptr, out, N3_);
}

// Round 2
// 804.214 us; speedup vs baseline: 1.2773x; 1.0234x over previous
//
#include <hip/hip_runtime.h>

// SNN B=128, D0=512, T=512, dims 1024/1024/512, DECAY=0.5, THRESH=0.3
// Round 13: 2-phase double-buffered staging (T3-minimum) in both GEMM kernels.
//  - Per K-step: issue NEXT B tile's global_load_lds, compute CURRENT from LDS,
//    then one s_waitcnt vmcnt(0) + s_barrier. Stage latency hides under MFMA.
//  - snn_layer_bits: bits 16K + 2x32K B dbuf = 80 KB LDS, 2 blocks/CU.
//  - snn_layer0: 2x32K (Ah/Al/Bh/Bl) = 64 KB LDS, 2 blocks/CU.
//  - expand8 via p=v*0x8001 bit-spread: 3 ops/u32 (exact 0x3F80/0 patterns).
// MFMA sequence per acc element identical to r12 (absmax=0 preserved).

typedef __bf16 bf16;
typedef __attribute__((ext_vector_type(8))) __bf16 bf16x8;
typedef __attribute__((ext_vector_type(16))) float f32x16;
typedef unsigned long long u64;

#define B_   128
#define D0_  512
#define T_   512
#define TS_  128
#define N1_  1024
#define N2_  1024
#define N3_  512
#define MFMA32(a,b,c) __builtin_amdgcn_mfma_f32_32x32x16_bf16((a),(b),(c),0,0,0)

#define GL2LDS(g, l) __builtin_amdgcn_global_load_lds( \
    (const __attribute__((address_space(1))) void*)(g), \
    (__attribute__((address_space(3))) void*)(l), 16, 0, 0)

#define WAIT_BARRIER() do { \
    asm volatile("s_waitcnt vmcnt(0)" ::: "memory"); \
    __builtin_amdgcn_s_barrier(); } while (0)

// ---------- setup ----------

__global__ __launch_bounds__(256)
void split_w(const float* __restrict__ W, bf16* __restrict__ WTh, bf16* __restrict__ WTl,
             int K, int N)
{
    __shared__ float tile[32][33];
    const int k0 = blockIdx.x * 32, n0 = blockIdx.y * 32;
    const int tx = threadIdx.x & 31, ty = threadIdx.x >> 5;
#pragma unroll
    for (int r = 0; r < 4; ++r)
        tile[ty + r * 8][tx] = W[(size_t)(k0 + ty + r * 8) * N + n0 + tx];
    __syncthreads();
#pragma unroll
    for (int r = 0; r < 4; ++r) {
        int nl = ty + r * 8;
        float v = tile[tx][nl];
        bf16 h = (bf16)v;
        size_t o = (size_t)(n0 + nl) * K + k0 + tx;
        WTh[o] = h;
        WTl[o] = (bf16)(v - (float)h);
    }
}

// x [B][D0][T] fp32 -> Xh/Xl slice-major [s][b][tl][D0] bf16 (hi/lo)
__global__ __launch_bounds__(256)
void split_x(const float* __restrict__ in, bf16* __restrict__ Xh, bf16* __restrict__ Xl)
{
    __shared__ float tile[32][33];
    const int b = blockIdx.z, d0 = blockIdx.x * 32, t0 = blockIdx.y * 32;
    const int tx = threadIdx.x & 31, ty = threadIdx.x >> 5;
#pragma unroll
    for (int r = 0; r < 4; ++r)
        tile[ty + r * 8][tx] = in[((size_t)b * D0_ + d0 + ty + r * 8) * T_ + t0 + tx];
    __syncthreads();
    const int s = t0 >> 7;
#pragma unroll
    for (int r = 0; r < 4; ++r) {
        int t  = t0 + ty + r * 8;
        int tl = t & (TS_ - 1);
        float v = tile[tx][ty + r * 8];
        bf16 h = (bf16)v;
        size_t o = (((size_t)s * B_ + b) * TS_ + tl) * D0_ + d0 + tx;
        Xh[o] = h;
        Xl[o] = (bf16)(v - (float)h);
    }
}

// 8 bits -> bf16x8 of {0.0, 1.0} (exact).  p = v*0x8001 puts bit 2i at pos 2i
// and bit 2i+1 at pos 2i+16; ((p>>2i)&0x10001)*0x3F80 -> two bf16 halves.
__device__ __forceinline__ bf16x8 expand8(unsigned v)
{
    union { unsigned u[4]; bf16x8 h; } r;
    const unsigned p = v * 0x8001u;
#pragma unroll
    for (int i = 0; i < 4; ++i)
        r.u[i] = ((p >> (2 * i)) & 0x10001u) * 0x3F80u;
    return r.h;
}

// ---------- layer 0: Xh/Xl @ W0 (3-term), BK=32, 2-phase dbuf ----------
__global__ __launch_bounds__(256, 2)
void snn_layer0(const bf16* __restrict__ Ah, const bf16* __restrict__ Al,
                const bf16* __restrict__ WTh, const bf16* __restrict__ WTl,
                u64* __restrict__ bitsOut)
{
    constexpr int K = D0_;
    __shared__ char smem[65536];
    // buf0: Ah@0 Al@8K Bh@16K Bl@24K ; buf1: same +32K. If overlay @0 (buf0).
    bf16* sA0  = (bf16*)(smem);
    bf16* sAl0 = (bf16*)(smem + 8192);
    bf16* sB0  = (bf16*)(smem + 16384);
    bf16* sBl0 = (bf16*)(smem + 24576);
    bf16* sA1  = (bf16*)(smem + 32768);
    bf16* sAl1 = (bf16*)(smem + 40960);
    bf16* sB1  = (bf16*)(smem + 49152);
    bf16* sBl1 = (bf16*)(smem + 57344);
    float* If  = (float*)smem;                             // [2][64][64] f32

    const int tid = threadIdx.x, lane = tid & 63, w = tid >> 6;
    const int wm = w & 1, wn = w >> 1;
    const int l31 = lane & 31, kh = lane >> 5;
    const int b = blockIdx.x;
    const int nb = blockIdx.y * 128;

    const int i4 = lane >> 2, c4 = lane & 3;
    const int csrc = c4 ^ ((i4 >> 1) & 3);
    const bf16* gBh = WTh + (size_t)(nb + w * 32 + i4) * K + csrc * 8;
    const bf16* gBl = WTl + (size_t)(nb + w * 32 + i4) * K + csrc * 8;
    const int wT = w * 32 * 32;                            // wave's 2 KB LDS chunk

    int rA[2], rB[2], swA[2], swB[2];
#pragma unroll
    for (int i = 0; i < 2; ++i) {
        rA[i] = wm * 64 + i * 32 + l31;
        rB[i] = wn * 64 + i * 32 + l31;
        swA[i] = (rA[i] >> 1) & 3;
        swB[i] = (rB[i] >> 1) & 3;
    }

    float cm = 0.f, cs = 0.f;
    const int scol = tid & 63;
    float* Ifb = If + (tid >> 6) * 4096;

#define STAGE0(dA, dAl, dBh, dBl, go)                                          \
    do {                                                                       \
        _Pragma("unroll")                                                      \
        for (int inst = 0; inst < 2; ++inst) {                                 \
            GL2LDS(gA  + (size_t)(inst * 16) * K + (go), (dA)  + wT + inst * 16 * 32); \
            GL2LDS(gAl + (size_t)(inst * 16) * K + (go), (dAl) + wT + inst * 16 * 32); \
            GL2LDS(gBh + (size_t)(inst * 16) * K + (go), (dBh) + wT + inst * 16 * 32); \
            GL2LDS(gBl + (size_t)(inst * 16) * K + (go), (dBl) + wT + inst * 16 * 32); \
        }                                                                      \
    } while (0)

#define KSTEP0(cA, cAl, cBh, cBl)                                              \
    do {                                                                       \
        bf16x8 a[2][2], al2[2][2];                                             \
        _Pragma("unroll")                                                      \
        for (int mi = 0; mi < 2; ++mi)                                         \
            _Pragma("unroll")                                                  \
            for (int h = 0; h < 2; ++h) {                                      \
                const int off = rA[mi] * 32 + (((2 * h + kh) ^ swA[mi]) * 8);  \
                a[mi][h]   = *(const bf16x8*)((cA) + off);                     \
                al2[mi][h] = *(const bf16x8*)((cAl) + off);                    \
            }                                                                  \
        _Pragma("unroll")                                                      \
        for (int ni = 0; ni < 2; ++ni) {                                       \
            _Pragma("unroll")                                                  \
            for (int h = 0; h < 2; ++h) {                                      \
                const int off = rB[ni] * 32 + (((2 * h + kh) ^ swB[ni]) * 8);  \
                bf16x8 bh = *(const bf16x8*)((cBh) + off);                     \
                bf16x8 bl = *(const bf16x8*)((cBl) + off);                     \
                _Pragma("unroll")                                              \
                for (int mi = 0; mi < 2; ++mi) {                               \
                    acc[mi][ni] = MFMA32(a[mi][h], bh, acc[mi][ni]);           \
                    acc[mi][ni] = MFMA32(al2[mi][h], bh, acc[mi][ni]);         \
                    acc[mi][ni] = MFMA32(a[mi][h], bl, acc[mi][ni]);           \
                }                                                              \
            }                                                                  \
        }                                                                      \
        WAIT_BARRIER();                                                        \
    } while (0)

#pragma unroll 1
    for (int s = 0; s < T_ / TS_; ++s) {
        const size_t arow = ((size_t)s * B_ + b) * TS_;
        const bf16* gA  = Ah + (arow + w * 32 + i4) * K + csrc * 8;
        const bf16* gAl = Al + (arow + w * 32 + i4) * K + csrc * 8;

        // prologue: stage ks=0 into buf0
        STAGE0(sA0, sAl0, sB0, sBl0, 0);
        WAIT_BARRIER();

        f32x16 acc[2][2] = {};

#pragma unroll 1
        for (int ks = 0; ks < K / 32; ks += 2) {
            // even step: compute buf0, prefetch ks+1 -> buf1
            STAGE0(sA1, sAl1, sB1, sBl1, (ks + 1) * 32);
            KSTEP0(sA0, sAl0, sB0, sBl0);
            // odd step: compute buf1, prefetch ks+2 -> buf0 (unless last)
            if (ks + 2 < K / 32)
                STAGE0(sA0, sAl0, sB0, sBl0, (ks + 2) * 32);
            KSTEP0(sA1, sAl1, sB1, sBl1);
        }

        // ---- epilogue: 2-phase LIF scan, ballot bit-transpose store ----
        // (final KSTEP0 barrier separates K-loop reads from If writes; buf0
        //  region (=If) was last read two barriers ago)
        u64 word0 = 0, word1 = 0;
        if (wm == 0) {
#pragma unroll
            for (int ni = 0; ni < 2; ++ni)
#pragma unroll
                for (int mi = 0; mi < 2; ++mi)
#pragma unroll
                    for (int r = 0; r < 16; ++r) {
                        const int tt = mi * 32 + (r & 3) + 8 * (r >> 2) + 4 * kh;
                        If[wn * 4096 + tt * 64 + ni * 32 + l31] = acc[mi][ni][r];
                    }
        }
        __syncthreads();
        if (tid < 128) {
            float m = cm, sp = cs;
#pragma unroll 4
            for (int tt = 0; tt < 64; ++tt) {
                m = m * 0.5f * (1.0f - sp) + Ifb[tt * 64 + scol];
                const bool fire = m > 0.3f;
                sp = fire ? 1.0f : 0.0f;
                u64 bal = __ballot(fire);
                if ((tid & 63) == tt) word0 = bal;
            }
            cm = m; cs = sp;
        }
        __syncthreads();
        if (wm == 1) {
#pragma unroll
            for (int ni = 0; ni < 2; ++ni)
#pragma unroll
                for (int mi = 0; mi < 2; ++mi)
#pragma unroll
                    for (int r = 0; r < 16; ++r) {
                        const int tt = mi * 32 + (r & 3) + 8 * (r >> 2) + 4 * kh;
                        If[wn * 4096 + tt * 64 + ni * 32 + l31] = acc[mi][ni][r];
                    }
        }
        __syncthreads();
        if (tid < 128) {
            float m = cm, sp = cs;
#pragma unroll 4
            for (int tt = 0; tt < 64; ++tt) {
                m = m * 0.5f * (1.0f - sp) + Ifb[tt * 64 + scol];
                const bool fire = m > 0.3f;
                sp = fire ? 1.0f : 0.0f;
                u64 bal = __ballot(fire);
                if ((tid & 63) == tt) word1 = bal;
            }
            cm = m; cs = sp;
            u64* dst = bitsOut + ((size_t)s * B_ + b) * 2048;  // 128 rows x 16 u64
            const int j8 = (nb >> 6) + (tid >> 6);
            const int t0 = tid & 63, t1 = 64 + (tid & 63);
            dst[t0 * 16 + (j8 ^ (t0 & 15))] = word0;
            dst[t1 * 16 + (j8 ^ (t1 & 15))] = word1;
        }
        __syncthreads();   // protect If (buf0) before next slice's prologue
    }
#undef STAGE0
#undef KSTEP0
}

// ---------- layers 1/2: bit-packed A, BK=64, 2-phase dbuf ----------
template<bool WRITE_BITS>
__global__ __launch_bounds__(256, 2)
void snn_layer_bits(const u64* __restrict__ bitsIn,
                    const bf16* __restrict__ WTh, const bf16* __restrict__ WTl,
                    u64* __restrict__ bitsOut, float* __restrict__ outp, int N)
{
    constexpr int K = 1024;
    __shared__ char smem[81920];
    char* bitsLds = smem;                       // [0,16K): bit tile [128 t][128 B]
    bf16* sBh0 = (bf16*)(smem + 16384);         // buf0 hi [128][64]
    bf16* sBl0 = (bf16*)(smem + 32768);         // buf0 lo
    bf16* sBh1 = (bf16*)(smem + 49152);         // buf1 hi
    bf16* sBl1 = (bf16*)(smem + 65536);         // buf1 lo
    float* If  = (float*)(smem + 16384);        // epilogue overlay (32 KB, =buf0)

    const int tid = threadIdx.x, lane = tid & 63, w = tid >> 6;
    const int wm = w & 1, wn = w >> 1;
    const int l31 = lane & 31, kh = lane >> 5;
    const int b = blockIdx.x;
    const int nb = blockIdx.y * 128;

    // B staging geometry (BK=64): lane = (row i8, chunk c8); chunk pre-swizzled
    const int i8 = lane >> 3, c8 = lane & 7;
    const bf16* gBh = WTh + (size_t)(nb + w * 32 + i8) * K + (c8 ^ i8) * 8;
    const bf16* gBl = WTl + (size_t)(nb + w * 32 + i8) * K + (c8 ^ i8) * 8;
    const int wB = w * 32 * 64;                 // wave's 4 KB LDS chunk

    int rA[2], rB[2];
#pragma unroll
    for (int i = 0; i < 2; ++i) {
        rA[i] = wm * 64 + i * 32 + l31;
        rB[i] = wn * 64 + i * 32 + l31;
    }
    const int sw7 = l31 & 7, sw15 = l31 & 15, sh8 = 8 * kh;

    float cm = 0.f, cs = 0.f;
    const int scol = tid & 63;
    float* Ifb = If + (tid >> 6) * 4096;

#define STAGEB(dBh, dBl, go)                                                   \
    do {                                                                       \
        _Pragma("unroll")                                                      \
        for (int inst = 0; inst < 4; ++inst) {                                 \
            GL2LDS(gBh + (size_t)(inst * 8) * K + (go), (dBh) + wB + inst * 8 * 64); \
            GL2LDS(gBl + (size_t)(inst * 8) * K + (go), (dBl) + wB + inst * 8 * 64); \
        }                                                                      \
    } while (0)

#define KSTEPB(ks, cBh, cBl)                                                   \
    do {                                                                       \
        u64 wA0 = *(const u64*)(bitsLds + rA[0] * 128 + (((ks) ^ sw15) << 3)) >> sh8; \
        u64 wA1 = *(const u64*)(bitsLds + rA[1] * 128 + (((ks) ^ sw15) << 3)) >> sh8; \
        _Pragma("unroll")                                                      \
        for (int h = 0; h < 4; ++h) {                                          \
            bf16x8 a0 = expand8((unsigned)(wA0 >> (16 * h)) & 0xFFu);          \
            bf16x8 a1 = expand8((unsigned)(wA1 >> (16 * h)) & 0xFFu);          \
            _Pragma("unroll")                                                  \
            for (int ni = 0; ni < 2; ++ni) {                                   \
                const int off = rB[ni] * 64 + (((2 * h + kh) ^ sw7) << 3);     \
                bf16x8 bh = *(const bf16x8*)((cBh) + off);                     \
                bf16x8 bl = *(const bf16x8*)((cBl) + off);                     \
                acc[0][ni] = MFMA32(a0, bh, acc[0][ni]);                       \
                acc[0][ni] = MFMA32(a0, bl, acc[0][ni]);                       \
                acc[1][ni] = MFMA32(a1, bh, acc[1][ni]);                       \
                acc[1][ni] = MFMA32(a1, bl, acc[1][ni]);                       \
            }                                                                  \
        }                                                                      \
        WAIT_BARRIER();                                                        \
    } while (0)

#pragma unroll 1
    for (int s = 0; s < T_ / TS_; ++s) {
        // prologue: stage bit tile (16 KB) + B(ks=0) -> buf0
        {
            const char* src = (const char*)bitsIn + ((size_t)s * B_ + b) * 16384;
#pragma unroll
            for (int i = 0; i < 4; ++i)
                GL2LDS(src + (w * 4 + i) * 1024 + lane * 16,
                       bitsLds + (w * 4 + i) * 1024);
        }
        STAGEB(sBh0, sBl0, 0);
        WAIT_BARRIER();

        f32x16 acc[2][2] = {};

#pragma unroll 1
        for (int ks = 0; ks < K / 64; ks += 2) {
            // even step: compute buf0, prefetch ks+1 -> buf1
            STAGEB(sBh1, sBl1, (ks + 1) * 64);
            KSTEPB(ks, sBh0, sBl0);
            // odd step: compute buf1, prefetch ks+2 -> buf0 (unless last)
            if (ks + 2 < K / 64)
                STAGEB(sBh0, sBl0, (ks + 2) * 64);
            KSTEPB(ks + 1, sBh1, sBl1);
        }

        // ---- epilogue: 2-phase LIF scan + ballot bit-transpose ----
        u64 word0 = 0, word1 = 0;
        if (wm == 0) {
#pragma unroll
            for (int ni = 0; ni < 2; ++ni)
#pragma unroll
                for (int mi = 0; mi < 2; ++mi)
#pragma unroll
                    for (int r = 0; r < 16; ++r) {
                        const int tt = mi * 32 + (r & 3) + 8 * (r >> 2) + 4 * kh;
                        If[wn * 4096 + tt * 64 + ni * 32 + l31] = acc[mi][ni][r];
                    }
        }
        __syncthreads();
        if (tid < 128) {
            float m = cm, sp = cs;
#pragma unroll 4
            for (int tt = 0; tt < 64; ++tt) {
                m = m * 0.5f * (1.0f - sp) + Ifb[tt * 64 + scol];
                const bool fire = m > 0.3f;
                sp = fire ? 1.0f : 0.0f;
                if constexpr (WRITE_BITS) {
                    u64 bal = __ballot(fire);
                    if ((tid & 63) == tt) word0 = bal;
                }
            }
            cm = m; cs = sp;
        }
        __syncthreads();
        if (wm == 1) {
#pragma unroll
            for (int ni = 0; ni < 2; ++ni)
#pragma unroll
                for (int mi = 0; mi < 2; ++mi)
#pragma unroll
                    for (int r = 0; r < 16; ++r) {
                        const int tt = mi * 32 + (r & 3) + 8 * (r >> 2) + 4 * kh;
                        If[wn * 4096 + tt * 64 + ni * 32 + l31] = acc[mi][ni][r];
                    }
        }
        __syncthreads();
        if (tid < 128) {
            float m = cm, sp = cs;
#pragma unroll 4
            for (int tt = 0; tt < 64; ++tt) {
                m = m * 0.5f * (1.0f - sp) + Ifb[tt * 64 + scol];
                const bool fire = m > 0.3f;
                sp = fire ? 1.0f : 0.0f;
                if constexpr (WRITE_BITS) {
                    u64 bal = __ballot(fire);
                    if ((tid & 63) == tt) word1 = bal;
                }
            }
            cm = m; cs = sp;
            if constexpr (WRITE_BITS) {
                u64* dst = bitsOut + ((size_t)s * B_ + b) * 2048;
                const int j8 = (nb >> 6) + (tid >> 6);
                const int t0 = tid & 63, t1 = 64 + (tid & 63);
                dst[t0 * 16 + (j8 ^ (t0 & 15))] = word0;
                dst[t1 * 16 + (j8 ^ (t1 & 15))] = word1;
            } else {
                if (s == T_ / TS_ - 1)
                    outp[(size_t)b * N + nb + tid] = cs;   // spike at t=511
            }
        }
        __syncthreads();   // protect If (buf0) before next slice's prologue
    }
#undef STAGEB
#undef KSTEPB
}

extern "C" void kernel_launch(void* const* d_in, const int* in_sizes, int n_in,
                              void* d_out, int out_size, void* d_ws, size_t ws_size,
                              hipStream_t stream)
{
    const float* x  = (const float*)d_in[0];
    const float* w0 = (const float*)d_in[1];
    const float* w1 = (const float*)d_in[2];
    const float* w2 = (const float*)d_in[3];
    float* out = (float*)d_out;

    char* p = (char*)d_ws;
    bf16* w0h = (bf16*)p;  p += (size_t)N1_ * D0_ * 2;
    bf16* w0l = (bf16*)p;  p += (size_t)N1_ * D0_ * 2;
    bf16* w1h = (bf16*)p;  p += (size_t)N2_ * N1_ * 2;
    bf16* w1l = (bf16*)p;  p += (size_t)N2_ * N1_ * 2;
    bf16* w2h = (bf16*)p;  p += (size_t)N3_ * N2_ * 2;
    bf16* w2l = (bf16*)p;  p += (size_t)N3_ * N2_ * 2;
    bf16* Xh  = (bf16*)p;  p += (size_t)T_ * B_ * D0_ * 2;          // 67 MB
    bf16* Xl  = (bf16*)p;  p += (size_t)T_ * B_ * D0_ * 2;          // 67 MB
    u64* bits0 = (u64*)p;  p += (size_t)(T_/TS_) * B_ * TS_ * (N1_/8);  // 8.4 MB
    u64* bits1 = (u64*)p;  p += (size_t)(T_/TS_) * B_ * TS_ * (N2_/8);  // 8.4 MB

    split_w<<<dim3(D0_/32, N1_/32), 256, 0, stream>>>(w0, w0h, w0l, D0_, N1_);
    split_w<<<dim3(N1_/32, N2_/32), 256, 0, stream>>>(w1, w1h, w1l, N1_, N2_);
    split_w<<<dim3(N2_/32, N3_/32), 256, 0, stream>>>(w2, w2h, w2l, N2_, N3_);
    split_x<<<dim3(D0_/32, T_/32, B_), 256, 0, stream>>>(x, Xh, Xl);

    // L0: X@w0 (3-term split) + LIF -> bit train
    snn_layer0<<<dim3(B_, N1_/128), 256, 0, stream>>>(Xh, Xl, w0h, w0l, bits0);
    // L1: bits0@w1 + LIF -> bit train
    snn_layer_bits<true ><<<dim3(B_, N2_/128), 256, 0, stream>>>(
        bits0, w1h, w1l, bits1, nullptr, N2_);
    // L2: bits1@w2 + LIF -> final spikes to d_out
    snn_layer_bits<false><<<dim3(B_, N3_/128), 256, 0, stream>>>(
        bits1, w2h, w2l, nullptr, out, N3_);
}